// Round 3
// baseline (201.460 us; speedup 1.0000x reference)
//
#include <hip/hip_runtime.h>
#include <stdint.h>

// out[r][c] = Y[r][c];  out[r][x[j]] += dt^2 * (deno @ X)[r][j]
// M = N = K = 4096, S = 64, dt^2 = 1e-6. Y/X/deno/out are FP32, x int32.

#define MDIM 4096
#define NDIM 4096
#define SDIM 64
#define KDIM 4096

typedef __bf16 bf16x8 __attribute__((ext_vector_type(8)));
typedef float  f32x4  __attribute__((ext_vector_type(4)));

union ABits { uint4 u; bf16x8 v; };

// ---------- 1. XT[n][k] = bf16(X[k][n])  (XT: [64][4096] ushort) ----------
__global__ __launch_bounds__(256) void k_transpose(const float* __restrict__ X,
                                                   unsigned short* __restrict__ XT) {
    int g = blockIdx.x * 256 + threadIdx.x;   // 0 .. 64*4096-1
    int n = g >> 12;
    int k = g & (KDIM - 1);
    union { float f; unsigned int u; } c;
    c.f = X[k * SDIM + n];                    // strided read, X=1MB L1/L2-resident
    XT[g] = (unsigned short)(c.u >> 16);      // truncate to bf16
}

// ---------- 2. pure fp32 copy: out = Y ----------
__global__ __launch_bounds__(256) void k_copy(const float4* __restrict__ Y4,
                                              float4* __restrict__ out4) {
    int g = blockIdx.x * 256 + threadIdx.x;
    out4[g] = Y4[g];
}

// ---------- 3. GEMM (bf16 MFMA, fp32 inputs converted on the fly) + scatter ----------
// Block = 16 rows x 64 cols of src = deno@X. 8 waves split K (512 each), no
// LDS in the K-loop (B frags are contiguous 16B loads from XT; A converted
// from fp32 via truncation). LDS only for the final 8-way reduction.
// mfma_f32_16x16x32_bf16 layouts (HW-verified, guide §3):
//   A[m][k]: m = lane&15, k = (lane>>4)*8 + j
//   B[k][n]: n = lane&15, k = (lane>>4)*8 + j  (XT stored [n][k])
//   D: col = lane&15, row = (lane>>4)*4 + reg
__global__ __launch_bounds__(512) void k_gemm_scatter(
    const float* __restrict__ deno, const unsigned short* __restrict__ XT,
    const float* __restrict__ Y, const int* __restrict__ x,
    float* __restrict__ out) {

    __shared__ float red[8][1024];   // per-wave partials: 16 rows x 64 cols

    const int t    = threadIdx.x;
    const int w    = t >> 6;         // 0..7
    const int lane = t & 63;
    const int r15  = lane & 15;
    const int q    = lane >> 4;
    const int m0   = blockIdx.x * 16;
    const int kw   = w * (KDIM / 8); // this wave's K range (512)

    const float*          ap  = deno + (size_t)(m0 + r15) * KDIM + kw + q * 8;
    const unsigned short* bp0 = XT + (size_t)(r15 +  0) * KDIM + kw + q * 8;
    const unsigned short* bp1 = XT + (size_t)(r15 + 16) * KDIM + kw + q * 8;
    const unsigned short* bp2 = XT + (size_t)(r15 + 32) * KDIM + kw + q * 8;
    const unsigned short* bp3 = XT + (size_t)(r15 + 48) * KDIM + kw + q * 8;

    f32x4 acc0 = {0.f,0.f,0.f,0.f}, acc1 = {0.f,0.f,0.f,0.f};
    f32x4 acc2 = {0.f,0.f,0.f,0.f}, acc3 = {0.f,0.f,0.f,0.f};

#pragma unroll 4
    for (int it = 0; it < 16; ++it) {
        // A: 8 fp32 -> 8 bf16 (truncation; dt^2 scaling makes the error ~1e-6)
        uint4 lo = *(const uint4*)(ap);
        uint4 hi = *(const uint4*)(ap + 4);
        ABits a;
        a.u.x = (lo.y & 0xFFFF0000u) | (lo.x >> 16);
        a.u.y = (lo.w & 0xFFFF0000u) | (lo.z >> 16);
        a.u.z = (hi.y & 0xFFFF0000u) | (hi.x >> 16);
        a.u.w = (hi.w & 0xFFFF0000u) | (hi.z >> 16);

        bf16x8 b0 = *(const bf16x8*)bp0;
        bf16x8 b1 = *(const bf16x8*)bp1;
        bf16x8 b2 = *(const bf16x8*)bp2;
        bf16x8 b3 = *(const bf16x8*)bp3;

        acc0 = __builtin_amdgcn_mfma_f32_16x16x32_bf16(a.v, b0, acc0, 0, 0, 0);
        acc1 = __builtin_amdgcn_mfma_f32_16x16x32_bf16(a.v, b1, acc1, 0, 0, 0);
        acc2 = __builtin_amdgcn_mfma_f32_16x16x32_bf16(a.v, b2, acc2, 0, 0, 0);
        acc3 = __builtin_amdgcn_mfma_f32_16x16x32_bf16(a.v, b3, acc3, 0, 0, 0);

        ap += 32; bp0 += 32; bp1 += 32; bp2 += 32; bp3 += 32;
    }

    // per-wave partials to LDS
#pragma unroll
    for (int reg = 0; reg < 4; ++reg) {
        const int rl = q * 4 + reg;
        red[w][rl * 64 +  0 + r15] = acc0[reg];
        red[w][rl * 64 + 16 + r15] = acc1[reg];
        red[w][rl * 64 + 32 + r15] = acc2[reg];
        red[w][rl * 64 + 48 + r15] = acc3[reg];
    }
    __syncthreads();

    // reduce 8 waves + write scatter columns: out[r][x[c]] = Y[r][x[c]] + dt^2*s
#pragma unroll
    for (int i = 0; i < 2; ++i) {
        const int idx = t + 512 * i;               // 0..1023
        float s = 0.f;
#pragma unroll
        for (int ww = 0; ww < 8; ++ww) s += red[ww][idx];
        const int rl  = idx >> 6;                  // local row 0..15
        const int c   = idx & 63;                  // src col 0..63
        const size_t a = (size_t)(m0 + rl) * NDIM + x[c];
        out[a] = Y[a] + 1e-6f * s;                 // dt^2 = 1e-6
    }
}

extern "C" void kernel_launch(void* const* d_in, const int* in_sizes, int n_in,
                              void* d_out, int out_size, void* d_ws, size_t ws_size,
                              hipStream_t stream) {
    const float* Y    = (const float*)d_in[0];
    const float* X    = (const float*)d_in[1];
    const float* deno = (const float*)d_in[2];
    const int*   x    = (const int*)d_in[3];

    unsigned short* XT = (unsigned short*)d_ws;    // 64*4096*2 B = 512 KB

    k_transpose<<<(SDIM * KDIM) / 256, 256, 0, stream>>>(X, XT);

    // full fp32 copy: 16777216 floats / 4 per thread / 256 per block = 16384 blocks
    k_copy<<<(MDIM * NDIM) / 4 / 256, 256, 0, stream>>>((const float4*)Y, (float4*)d_out);

    k_gemm_scatter<<<MDIM / 16, 512, 0, stream>>>(deno, XT, Y, x, (float*)d_out);
}